// Round 6
// baseline (304.623 us; speedup 1.0000x reference)
//
#include <hip/hip_runtime.h>

#define BB 64
#define PP 8732
#define OO 32
#define CC 81
#define NEGPOS 3
#define NCH_B 32                   // per-object chunks: 32*273 = 8736 >= 8732
#define CHB 273
#define NCEB 137                   // ce chunk-slots per batch (64 priors each)
#define NCE2 69                    // ce blocks per batch: 69*128 = 8832 >= 8732

typedef float f32x4 __attribute__((ext_vector_type(4), aligned(4)));

// ---------------- workspace layout (poison-proof: every word written before read) ----
// cepos/lsum/npos are PER-WAVE partials: [B][NCEB][4] (slot = old 16-prior wave).
#define WS_BESTP  0                              // u64 bestp[B*NCH_B*OO]
#define WS_CENEG  (WS_BESTP + BB*NCH_B*OO*8)     // f32 ce_neg[B*PP]
#define WS_CEPOS  (WS_CENEG + BB*PP*4)           // f32 cepos4[B*NCEB*4]
#define WS_LSUMB  (WS_CEPOS + BB*NCEB*16)        // f32 lsum4[B*NCEB*4]
#define WS_NPOSB  (WS_LSUMB + BB*NCEB*16)        // i32 npos4[B*NCEB*4]
#define WS_HARDB  (WS_NPOSB + BB*NCEB*16)        // f32 hard_b[B]
#define WS_DONE   (WS_HARDB + BB*4)              // int done

// ---------------- kernel 1: per-object argmax over priors (chunked partials) --------
// grid (NCH_B, B) x 512. 16 sub-lanes per object scan a 273-prior chunk.
__global__ __launch_bounds__(512) void match_obj(
    const float* __restrict__ boxes, const float* __restrict__ priors,
    unsigned long long* __restrict__ bestp, int* __restrict__ done)
{
    const int b = blockIdx.y, ch = blockIdx.x, tid = threadIdx.x;
    __shared__ float sbx[OO * 4];
    __shared__ unsigned long long sred[8 * OO];
    if (tid < OO * 4) sbx[tid] = boxes[b * OO * 4 + tid];
    if (ch == 0 && b == 0 && tid == 0) *done = 0;   // ticket for topk's fused finalize
    __syncthreads();

    const int o = tid & 31, sub = tid >> 5;            // sub 0..15
    const float b0 = sbx[o*4+0], b1 = sbx[o*4+1], b2 = sbx[o*4+2], b3 = sbx[o*4+3];
    const float barea = (b2 - b0) * (b3 - b1);
    const int base = ch * CHB;
    unsigned long long best = 0ull;
    for (int i = sub; i < CHB; i += 16) {
        int p = base + i;
        if (p >= PP) break;
        float4 pr = ((const float4*)priors)[p];
        float plx = pr.x - pr.z * 0.5f, ply = pr.y - pr.w * 0.5f;
        float phx = pr.x + pr.z * 0.5f, phy = pr.y + pr.w * 0.5f;
        float parea = pr.z * pr.w;
        float lox = fmaxf(b0, plx), loy = fmaxf(b1, ply);
        float hix = fminf(b2, phx), hiy = fminf(b3, phy);
        float inter = fmaxf(hix - lox, 0.0f) * fmaxf(hiy - loy, 0.0f);
        float iou = inter / (barea + parea - inter);
        unsigned long long enc =
            ((unsigned long long)__float_as_uint(iou) << 32) | (unsigned)(~(unsigned)p);
        best = (enc > best) ? enc : best;              // max iou, tie -> min p
    }
    unsigned long long w = __shfl_down(best, 32, 64);  // lanes l / l+32 share object
    best = (w > best) ? w : best;
    const int wid = tid >> 6, lane = tid & 63;
    if (lane < 32) sred[wid * OO + o] = best;
    __syncthreads();
    if (tid < OO) {
        unsigned long long m = 0ull;
#pragma unroll
        for (int wv = 0; wv < 8; ++wv) {
            unsigned long long v = sred[wv * OO + tid];
            m = (v > m) ? v : m;
        }
        bestp[(b * NCH_B + ch) * OO + tid] = m;
    }
}

// ---------------- per-prior CE body (verbatim round-5 arithmetic) -------------------
__device__ __forceinline__ void ce_body(
    const float d[21], const float* __restrict__ priors,
    const float* sbx, const int* slab, const int* sovr,
    const float* __restrict__ pred_locs, float* __restrict__ ce_neg,
    long long bp, int p, int lp, int j,
    float& posc, float& lsum, int& lpos)
{
    // ---- in-register per-prior argmax: lane j scans objects j*8..j*8+7 ----
    float4 pr = ((const float4*)priors)[p];
    float plx = pr.x - pr.z * 0.5f, ply = pr.y - pr.w * 0.5f;
    float phx = pr.x + pr.z * 0.5f, phy = pr.y + pr.w * 0.5f;
    float parea = pr.z * pr.w;
    unsigned long long eb = 0ull;
#pragma unroll
    for (int k = 0; k < 8; ++k) {
        const int oo = j * 8 + k;
        float c0 = sbx[oo*4+0], c1 = sbx[oo*4+1], c2 = sbx[oo*4+2], c3 = sbx[oo*4+3];
        float lox = fmaxf(c0, plx), loy = fmaxf(c1, ply);
        float hix = fminf(c2, phx), hiy = fminf(c3, phy);
        float inter = fmaxf(hix - lox, 0.0f) * fmaxf(hiy - loy, 0.0f);
        float iou = inter / ((c2 - c0) * (c3 - c1) + parea - inter);
        unsigned long long enc =
            ((unsigned long long)__float_as_uint(iou) << 32) | (unsigned)(~(unsigned)oo);
        eb = (enc > eb) ? enc : eb;            // max iou, tie -> min o (np first-max)
    }
    {
        unsigned long long t = __shfl_xor(eb, 1, 64); eb = (t > eb) ? t : eb;
        t = __shfl_xor(eb, 2, 64);                    eb = (t > eb) ? t : eb;
    }
    int o = (int)(~(unsigned)(eb & 0xFFFFFFFFull));
    float ov = __uint_as_float((unsigned)(eb >> 32));

    // forced-positive override via LDS flag (atomicMax oo == last-write-wins)
    {
        int oa = sovr[lp];
        if (oa >= 0) { o = oa; ov = 1.0f; }
    }
    const int l = (ov < 0.5f) ? 0 : slab[o];

    float m = d[20];
#pragma unroll
    for (int i = 0; i < 20; ++i) m = fmaxf(m, d[i]);
    m = fmaxf(m, __shfl_xor(m, 1, 64));
    m = fmaxf(m, __shfl_xor(m, 2, 64));

    float s = 0.0f;
#pragma unroll
    for (int i = 0; i < 21; ++i) s += __expf(d[i] - m);   // j!=0: d[20] underflows to 0

    float vl = 0.0f;                           // score at the label class
    if (l == 80) { if (j == 0) vl = d[20]; }
    else { int c = l >> 2; if ((c & 3) == j) vl = d[4 * (c >> 2) + (l & 3)]; }

    s  += __shfl_xor(s, 1, 64);   s  += __shfl_xor(s, 2, 64);
    vl += __shfl_xor(vl, 1, 64);  vl += __shfl_xor(vl, 2, 64);

    float ce = m + __logf(s) - vl;
    if (j == 0) {
        ce_neg[bp] = (l != 0) ? 0.0f : ce;
        if (l != 0) {
            posc = ce; lpos = 1;
            float b0 = sbx[o*4+0], b1 = sbx[o*4+1], b2 = sbx[o*4+2], b3 = sbx[o*4+3];
            float gx = ((b0 + b2) * 0.5f - pr.x) / (pr.z * 0.1f);
            float gy = ((b1 + b3) * 0.5f - pr.y) / (pr.w * 0.1f);
            float gw = logf((b2 - b0) / pr.z) * 5.0f;
            float gh = logf((b3 - b1) / pr.w) * 5.0f;
            float4 pl = ((const float4*)pred_locs)[bp];
            lsum = fabsf(pl.x - gx) + fabsf(pl.y - gy)
                 + fabsf(pl.z - gw) + fabsf(pl.w - gh);
        }
    }
}

// ---------------- kernel 2: fused streaming CE, 2 priors per 4-lane group -----------
// grid (NCE2, B) x 256: each wave covers 32 priors = two old 16-prior slots
// (A = first 16, B = +16). Lane->prior mapping inside the wave is IDENTICAL to the
// old wave for old chunk 2ch+(w>>1), old waves (w&1)*2 / (w&1)*2+1, so running the
// same shfl_down tree on A-values and B-values reproduces the old [B][137][4]
// partial slots bit-identically. 12 score-load instrs issued before any consumption:
// B's HBM latency hides under A's argmax+softmax VALU work.
__global__ __launch_bounds__(256) void ce_match(
    const float* __restrict__ scores, const float* __restrict__ pred_locs,
    const float* __restrict__ boxes, const int* __restrict__ labels,
    const float* __restrict__ priors,
    const unsigned long long* __restrict__ bestp,
    float* __restrict__ ce_neg, float* __restrict__ cepos4,
    float* __restrict__ lsum4, int* __restrict__ npos4)
{
    const int b = blockIdx.y, ch = blockIdx.x, tid = threadIdx.x;
    const int base = ch * 128;
    __shared__ float sbx[OO * 4];
    __shared__ int   slab[OO];
    __shared__ int   sovr[128];
    __shared__ unsigned long long sred[4 * OO];

    // ---- parallel bestp reduce: 1024 u64 per batch, 4 coalesced loads/thread ----
    {
        const unsigned long long* __restrict__ bp_ = bestp + (long long)b * (NCH_B * OO);
        unsigned long long m0 = bp_[tid];
        unsigned long long m1 = bp_[tid + 256];
        unsigned long long m2 = bp_[tid + 512];
        unsigned long long m3 = bp_[tid + 768];
        m0 = (m1 > m0) ? m1 : m0;
        m2 = (m3 > m2) ? m3 : m2;
        m0 = (m2 > m0) ? m2 : m0;                      // idx mod 32 == tid&31 (object)
        unsigned long long t2 = __shfl_down(m0, 32, 64);  // lanes l / l+32: same object
        m0 = (t2 > m0) ? t2 : m0;
        if ((tid & 63) < 32) sred[(tid >> 6) * OO + (tid & 31)] = m0;
    }
    if (tid < OO * 4) sbx[tid] = boxes[b * OO * 4 + tid];
    if (tid >= 224)   slab[tid - 224] = labels[b * OO + (tid - 224)];
    if (tid < 128)    sovr[tid] = -1;
    __syncthreads();
    if (tid < OO) {
        unsigned long long m = sred[tid];
#pragma unroll
        for (int w = 1; w < 4; ++w) {
            unsigned long long v = sred[w * OO + tid];
            m = (v > m) ? v : m;
        }
        const int pf = (int)(~(unsigned)(m & 0xFFFFFFFFull));
        const int local = pf - base;
        if (local >= 0 && local < 128) atomicMax(&sovr[local], tid);
    }
    __syncthreads();

    const int wv = tid >> 6, l = tid & 63;
    const int g = l >> 2, j = tid & 3;             // 4-lane group per prior
    const int lpA = wv * 32 + g, lpB = lpA + 16;   // local prior idx within block
    const int pA = base + lpA, pB = base + lpB;

    float poscA = 0.0f, lsumA = 0.0f; int lposA = 0;
    float poscB = 0.0f, lsumB = 0.0f; int lposB = 0;
    const long long bpA = (long long)b * PP + pA;
    const long long bpB = (long long)b * PP + pB;

    // ---- issue ALL 12 score loads up-front (MLP), then compute A, then B ----
    float dA[21], dB[21];
    const bool vA = pA < PP, vB = pB < PP;
    if (vA) {
        const float* __restrict__ v = scores + bpA * CC;
#pragma unroll
        for (int k = 0; k < 5; ++k) {
            f32x4 t4 = *(const f32x4*)(v + (4 * k + j) * 4);
            dA[4*k+0] = t4.x; dA[4*k+1] = t4.y; dA[4*k+2] = t4.z; dA[4*k+3] = t4.w;
        }
        dA[20] = (j == 0) ? v[80] : -3.0e38f;
    }
    if (vB) {
        const float* __restrict__ v = scores + bpB * CC;
#pragma unroll
        for (int k = 0; k < 5; ++k) {
            f32x4 t4 = *(const f32x4*)(v + (4 * k + j) * 4);
            dB[4*k+0] = t4.x; dB[4*k+1] = t4.y; dB[4*k+2] = t4.z; dB[4*k+3] = t4.w;
        }
        dB[20] = (j == 0) ? v[80] : -3.0e38f;
    }

    if (vA) ce_body(dA, priors, sbx, slab, sovr, pred_locs, ce_neg,
                    bpA, pA, lpA, j, poscA, lsumA, lposA);
    if (vB) ce_body(dB, priors, sbx, slab, sovr, pred_locs, ce_neg,
                    bpB, pB, lpB, j, poscB, lsumB, lposB);

    // ---- two old-tree reduces -> two old slots (bit-identical values) ----
    const int co = 2 * ch + (wv >> 1);             // old chunk index
    const int wA = (wv & 1) * 2;                   // old wave slot for A; B = wA+1
    for (int off = 32; off > 0; off >>= 1) {
        poscA += __shfl_down(poscA, off, 64);
        lsumA += __shfl_down(lsumA, off, 64);
        lposA += __shfl_down(lposA, off, 64);
    }
    for (int off = 32; off > 0; off >>= 1) {
        poscB += __shfl_down(poscB, off, 64);
        lsumB += __shfl_down(lsumB, off, 64);
        lposB += __shfl_down(lposB, off, 64);
    }
    if (l == 0 && co < NCEB) {
        const int idxA = (b * NCEB + co) * 4 + wA;
        cepos4[idxA]     = poscA;  lsum4[idxA]     = lsumA;  npos4[idxA]     = lposA;
        cepos4[idxA + 1] = poscB;  lsum4[idxA + 1] = lsumB;  npos4[idxA + 1] = lposB;
    }
}

// ---------------- kernel 3: per-batch exact top-K radix select (12+10+10 bits) ------
__device__ __forceinline__ void suffix_select(
    int* hist, int nbins, unsigned rem, unsigned* sel, int* wred, int tid)
{
    const int nb = nbins >> 9;          // bins per thread (512 threads)
    const int base = tid * nb;
    int tot = 0;
    for (int i = 0; i < nb; ++i) tot += hist[base + i];
    const int lane = tid & 63, w = tid >> 6;
    int s = tot;                         // inclusive suffix within wave
#pragma unroll
    for (int off = 1; off < 64; off <<= 1) {
        int v = __shfl_down(s, off, 64);
        if (lane + off < 64) s += v;
    }
    if (lane == 0) wred[w] = s;          // wave total
    __syncthreads();
    int after = s - tot;                 // suffix of lanes > lane within wave
    for (int ww = w + 1; ww < 8; ++ww) after += wred[ww];
    int cum = after;                     // suffixAfter(this thread's last bin)
    for (int i = nb - 1; i >= 0; --i) {
        int h = hist[base + i];
        if ((unsigned)cum < rem && (unsigned)(cum + h) >= rem) {
            sel[0] = (unsigned)(base + i);
            sel[1] = rem - (unsigned)cum;
        }
        cum += h;
    }
    __syncthreads();
}

// grid B x 512. Last block (ticket) runs the fused finalize.
__global__ __launch_bounds__(512) void topk_kernel(
    const float* __restrict__ ce_neg, const int* __restrict__ npos4,
    const float* __restrict__ cepos4, const float* __restrict__ lsum4,
    float* __restrict__ hard_b, int* __restrict__ done, float* __restrict__ out)
{
    __shared__ float sv[PP];          // 34928 B
    __shared__ int hist[4096];        // 16 KB, reused for the 1024-bin passes
    __shared__ int wred[8];
    __shared__ unsigned sel[2];
    __shared__ float sr[8];
    __shared__ int sKred[8];
    const int b = blockIdx.x, tid = threadIdx.x;

    for (int i = tid; i < 4096; i += 512) hist[i] = 0;
    {   // parallel K reduce over NCEB per-wave partials (ints: order-exact regardless)
        int n = 0;
        for (int c = tid; c < NCEB; c += 512) {
            const int4 nn = ((const int4*)npos4)[b * NCEB + c];
            n += ((nn.x + nn.y) + nn.z) + nn.w;
        }
        for (int off = 32; off > 0; off >>= 1) n += __shfl_down(n, off, 64);
        if ((tid & 63) == 0) sKred[tid >> 6] = n;
    }
    __syncthreads();

    // fused load + pass-1 histogram (u>>20 covers ALL u32 patterns: no range assumption)
    for (int p = tid; p < PP; p += 512) {
        float v = ce_neg[b * PP + p];
        sv[p] = v;
        atomicAdd(&hist[__float_as_uint(v) >> 20], 1);
    }
    int K;
    {
        int n = 0;
#pragma unroll
        for (int w = 0; w < 8; ++w) n += sKred[w];
        K = NEGPOS * n;
        if (K > PP) K = PP;
    }
    __syncthreads();

    float hard = 0.0f;
    if (K > 0) {
        suffix_select(hist, 4096, (unsigned)K, sel, wred, tid);
        const unsigned b1 = sel[0], rem1 = sel[1];

        for (int i = tid; i < 1024; i += 512) hist[i] = 0;
        __syncthreads();
        for (int p = tid; p < PP; p += 512) {
            unsigned u = __float_as_uint(sv[p]);
            if ((u >> 20) == b1) atomicAdd(&hist[(u >> 10) & 1023], 1);
        }
        __syncthreads();
        suffix_select(hist, 1024, rem1, sel, wred, tid);
        const unsigned b2 = sel[0], rem2 = sel[1];
        const unsigned pre2 = (b1 << 20) | (b2 << 10);

        for (int i = tid; i < 1024; i += 512) hist[i] = 0;
        __syncthreads();
        for (int p = tid; p < PP; p += 512) {
            unsigned u = __float_as_uint(sv[p]);
            if ((u >> 10) == (pre2 >> 10)) atomicAdd(&hist[u & 1023], 1);
        }
        __syncthreads();
        suffix_select(hist, 1024, rem2, sel, wred, tid);
        const unsigned prefix = pre2 | sel[0];
        const unsigned remaining = sel[1];

        // final sum: identical traversal/order to previous version -> bit-identical
        float sgt = 0.0f;
        for (int p = tid; p < PP; p += 512) {
            unsigned u = __float_as_uint(sv[p]);
            if (u > prefix) sgt += sv[p];
        }
        for (int off = 32; off > 0; off >>= 1) sgt += __shfl_down(sgt, off, 64);
        if ((tid & 63) == 0) sr[tid >> 6] = sgt;
        __syncthreads();
        if (tid == 0) {
            hard = 0.0f;
#pragma unroll
            for (int w = 0; w < 8; ++w) hard += sr[w];
            hard += __uint_as_float(prefix) * (float)remaining;
        }
    }
    __shared__ int sticket;
    if (tid == 0) {
        hard_b[b] = hard;
        __threadfence();                 // device-scope: flush before taking ticket
        sticket = atomicAdd(done, 1);
    }
    __syncthreads();
    if (sticket != BB - 1) return;

    // ---- fused finalize (last block only) ----
    // per-ch pre-sum ((w0+w1)+w2)+w3 replicates the old block-level sum exactly.
    float cpos = 0.0f, labs = 0.0f, chard = 0.0f; int n = 0;
    for (int i = tid; i < BB * NCEB; i += 512) {
        const float4 c4 = ((const float4*)cepos4)[i];
        const float4 l4 = ((const float4*)lsum4)[i];
        const int4  n4 = ((const int4*)npos4)[i];
        cpos += ((c4.x + c4.y) + c4.z) + c4.w;
        labs += ((l4.x + l4.y) + l4.z) + l4.w;
        n    += ((n4.x + n4.y) + n4.z) + n4.w;
    }
    if (tid < BB) chard = atomicAdd(&hard_b[tid], 0.0f);   // atomic load: XCD-coherent
    for (int off = 32; off > 0; off >>= 1) {
        cpos  += __shfl_down(cpos, off, 64);
        labs  += __shfl_down(labs, off, 64);
        chard += __shfl_down(chard, off, 64);
        n     += __shfl_down(n, off, 64);
    }
    __shared__ float f0[8], f1[8], f2[8];
    __shared__ int i3[8];
    if ((tid & 63) == 0) { int w = tid >> 6; f0[w] = cpos; f1[w] = labs; f2[w] = chard; i3[w] = n; }
    __syncthreads();
    if (tid == 0) {
        float a = 0.0f, bs = 0.0f, c = 0.0f; int nt = 0;
#pragma unroll
        for (int w = 0; w < 8; ++w) { a += f0[w]; bs += f1[w]; c += f2[w]; nt += i3[w]; }
        float nf = (float)nt;
        out[0] = (c + a) / nf + bs / (nf * 4.0f);
    }
}

extern "C" void kernel_launch(void* const* d_in, const int* in_sizes, int n_in,
                              void* d_out, int out_size, void* d_ws, size_t ws_size,
                              hipStream_t stream) {
    const float* pred_locs   = (const float*)d_in[0];   // [B,P,4]
    const float* pred_scores = (const float*)d_in[1];   // [B,P,C]
    const float* boxes       = (const float*)d_in[2];   // [B,O,4]
    const int*   labels      = (const int*)d_in[3];     // [B,O]
    const float* priors      = (const float*)d_in[4];   // [P,4] cxcywh
    float* out = (float*)d_out;

    char* ws = (char*)d_ws;
    unsigned long long* bestp = (unsigned long long*)(ws + WS_BESTP);
    float* ce_neg  = (float*)(ws + WS_CENEG);
    float* cepos4  = (float*)(ws + WS_CEPOS);
    float* lsum4   = (float*)(ws + WS_LSUMB);
    int*   npos4   = (int*)(ws + WS_NPOSB);
    float* hard_b  = (float*)(ws + WS_HARDB);
    int*   done    = (int*)(ws + WS_DONE);

    match_obj<<<dim3(NCH_B, BB), 512, 0, stream>>>(boxes, priors, bestp, done);
    ce_match<<<dim3(NCE2, BB), 256, 0, stream>>>(pred_scores, pred_locs, boxes, labels,
                                                 priors, bestp,
                                                 ce_neg, cepos4, lsum4, npos4);
    topk_kernel<<<BB, 512, 0, stream>>>(ce_neg, npos4, cepos4, lsum4, hard_b, done, out);
}